// Round 6
// baseline (890.615 us; speedup 1.0000x reference)
//
#include <hip/hip_runtime.h>
#include <stdint.h>

#define NN 50000
#define NE 800000
#define NG 512
#define H  128

__device__ __forceinline__ float softplusf(float x){
    return fmaxf(x, 0.f) + log1pf(expf(-fabsf(x)));
}

// ---------------- sentinel writer (debug channel through out[.]) ----------------
__global__ void k_sentinel(float* out, float val){
    int i = blockIdx.x*256 + threadIdx.x;
    if (i < 6*NG) out[i] = val;
}

// ---------------- fused initial embedding GEMM ----------------
// x = relu( concat(embed_tab[z], pos@W_pos+b_pos) @ W_comb + b_comb )
__global__ __launch_bounds__(256) void k_embed(const int* __restrict__ z,
    const float* __restrict__ pos, const float* __restrict__ emb,
    const float* __restrict__ Wp, const float* __restrict__ bp,
    const float* __restrict__ Wc, const float* __restrict__ bc,
    float* __restrict__ Y, int M)
{
    __shared__ float Xs[64*66];
    __shared__ float Ws[64*128];
    const int t  = threadIdx.x;
    const int tn = t & 15, tm = t >> 4;
    const int n0 = tn*8,  m0 = tm*4;
    const int mb = blockIdx.x*64;
    float acc[4][8];
#pragma unroll
    for (int i=0;i<4;i++)
#pragma unroll
      for (int j=0;j<8;j++) acc[i][j]=0.f;

    for (int k0=0; k0<256; k0+=64){
        {
            const int kq = t & 15, mr = t >> 4;
#pragma unroll
            for (int p=0;p<4;p++){
                int m = mr + p*16;
                int gr = mb + m;
                float4 v = make_float4(0.f,0.f,0.f,0.f);
                if (gr < M){
                    if (k0 < 128){
                        v = *(const float4*)(emb + (size_t)z[gr]*H + k0 + kq*4);
                    } else {
                        int c = (k0 - 128) + kq*4;
                        float4 w0 = *(const float4*)(Wp + c);
                        float4 w1 = *(const float4*)(Wp + H + c);
                        float4 w2 = *(const float4*)(Wp + 2*H + c);
                        float4 bb = *(const float4*)(bp + c);
                        float p0 = pos[gr*3+0], p1 = pos[gr*3+1], p2 = pos[gr*3+2];
                        v.x = p0*w0.x + p1*w1.x + p2*w2.x + bb.x;
                        v.y = p0*w0.y + p1*w1.y + p2*w2.y + bb.y;
                        v.z = p0*w0.z + p1*w1.z + p2*w2.z + bb.z;
                        v.w = p0*w0.w + p1*w1.w + p2*w2.w + bb.w;
                    }
                }
                float* d = &Xs[m*66 + kq*4];
                d[0]=v.x; d[1]=v.y; d[2]=v.z; d[3]=v.w;
            }
        }
        {
            const int kk = t >> 2, c0 = (t & 3)*32;
            const float4* wr = (const float4*)(Wc + (size_t)(k0+kk)*H + c0);
            float4* d = (float4*)&Ws[kk*H + c0];
#pragma unroll
            for (int q=0;q<8;q++) d[q] = wr[q];
        }
        __syncthreads();
#pragma unroll 8
        for (int kk=0; kk<64; kk++){
            float x0=Xs[(m0+0)*66+kk], x1=Xs[(m0+1)*66+kk];
            float x2=Xs[(m0+2)*66+kk], x3=Xs[(m0+3)*66+kk];
            const float4* wp = (const float4*)&Ws[kk*H + n0];
            float4 wa = wp[0], wb = wp[1];
            float w[8] = {wa.x,wa.y,wa.z,wa.w, wb.x,wb.y,wb.z,wb.w};
#pragma unroll
            for (int j=0;j<8;j++){
                acc[0][j] += x0*w[j];
                acc[1][j] += x1*w[j];
                acc[2][j] += x2*w[j];
                acc[3][j] += x3*w[j];
            }
        }
        __syncthreads();
    }
#pragma unroll
    for (int i=0;i<4;i++){
        int gr = mb + m0 + i;
        if (gr < M){
            float o[8];
#pragma unroll
            for (int j=0;j<8;j++) o[j] = fmaxf(acc[i][j] + bc[n0+j], 0.f);
            float4* yp = (float4*)(Y + (size_t)gr*H + n0);
            yp[0] = make_float4(o[0],o[1],o[2],o[3]);
            yp[1] = make_float4(o[4],o[5],o[6],o[7]);
        }
    }
}

// ---------------- fused GIN MLP: Y = act2( relu(Xin@W1+b1) @ W2 + b2 ) ----------------
__global__ __launch_bounds__(256) void k_gin_mlp(const float* __restrict__ Xin,
    const float* __restrict__ W1, const float* __restrict__ b1,
    const float* __restrict__ W2, const float* __restrict__ b2,
    float* __restrict__ Y, int M, int do_relu2)
{
    __shared__ float Xs[64*132];
    __shared__ float Ws[64*128];
    const int t  = threadIdx.x;
    const int tn = t & 15, tm = t >> 4;
    const int n0 = tn*8,  m0 = tm*4;
    const int mb = blockIdx.x*64;

    {
        const int kq = t & 31, mr = t >> 5;
#pragma unroll
        for (int p=0;p<8;p++){
            int m = mr + p*8;
            int gr = mb + m;
            float4 v = make_float4(0.f,0.f,0.f,0.f);
            if (gr < M) v = *(const float4*)(Xin + (size_t)gr*H + kq*4);
            float* d = &Xs[m*132 + kq*4];
            d[0]=v.x; d[1]=v.y; d[2]=v.z; d[3]=v.w;
        }
    }

    float acc[4][8];
#pragma unroll
    for (int i=0;i<4;i++)
#pragma unroll
      for (int j=0;j<8;j++) acc[i][j]=0.f;

    for (int k0=0; k0<H; k0+=64){
        { const int kk = t >> 2, c0 = (t & 3)*32;
          const float4* wr = (const float4*)(W1 + (size_t)(k0+kk)*H + c0);
          float4* d = (float4*)&Ws[kk*H + c0];
#pragma unroll
          for (int q=0;q<8;q++) d[q] = wr[q];
        }
        __syncthreads();
#pragma unroll 8
        for (int kk=0; kk<64; kk++){
            int k = k0 + kk;
            float x0=Xs[(m0+0)*132+k], x1=Xs[(m0+1)*132+k];
            float x2=Xs[(m0+2)*132+k], x3=Xs[(m0+3)*132+k];
            const float4* wp = (const float4*)&Ws[kk*H + n0];
            float4 wa = wp[0], wb = wp[1];
            float w[8] = {wa.x,wa.y,wa.z,wa.w, wb.x,wb.y,wb.z,wb.w};
#pragma unroll
            for (int j=0;j<8;j++){
                acc[0][j] += x0*w[j];
                acc[1][j] += x1*w[j];
                acc[2][j] += x2*w[j];
                acc[3][j] += x3*w[j];
            }
        }
        __syncthreads();
    }
#pragma unroll
    for (int i=0;i<4;i++)
#pragma unroll
      for (int j=0;j<8;j++)
        Xs[(m0+i)*132 + n0 + j] = fmaxf(acc[i][j] + b1[n0+j], 0.f);
    __syncthreads();

#pragma unroll
    for (int i=0;i<4;i++)
#pragma unroll
      for (int j=0;j<8;j++) acc[i][j]=0.f;

    for (int k0=0; k0<H; k0+=64){
        { const int kk = t >> 2, c0 = (t & 3)*32;
          const float4* wr = (const float4*)(W2 + (size_t)(k0+kk)*H + c0);
          float4* d = (float4*)&Ws[kk*H + c0];
#pragma unroll
          for (int q=0;q<8;q++) d[q] = wr[q];
        }
        __syncthreads();
#pragma unroll 8
        for (int kk=0; kk<64; kk++){
            int k = k0 + kk;
            float x0=Xs[(m0+0)*132+k], x1=Xs[(m0+1)*132+k];
            float x2=Xs[(m0+2)*132+k], x3=Xs[(m0+3)*132+k];
            const float4* wp = (const float4*)&Ws[kk*H + n0];
            float4 wa = wp[0], wb = wp[1];
            float w[8] = {wa.x,wa.y,wa.z,wa.w, wb.x,wb.y,wb.z,wb.w};
#pragma unroll
            for (int j=0;j<8;j++){
                acc[0][j] += x0*w[j];
                acc[1][j] += x1*w[j];
                acc[2][j] += x2*w[j];
                acc[3][j] += x3*w[j];
            }
        }
        __syncthreads();
    }
#pragma unroll
    for (int i=0;i<4;i++){
        int gr = mb + m0 + i;
        if (gr < M){
            float o[8];
#pragma unroll
            for (int j=0;j<8;j++){
                float v = acc[i][j] + b2[n0+j];
                o[j] = do_relu2 ? fmaxf(v, 0.f) : v;
            }
            float4* yp = (float4*)(Y + (size_t)gr*H + n0);
            yp[0] = make_float4(o[0],o[1],o[2],o[3]);
            yp[1] = make_float4(o[4],o[5],o[6],o[7]);
        }
    }
}

// ---------------- CSR build (by dst) ----------------
__global__ void k_zero(int* p, int n){ int i=blockIdx.x*256+threadIdx.x; if(i<n) p[i]=0; }

__global__ void k_count(const int* __restrict__ ei, int* __restrict__ cnt){
    int e = blockIdx.x*256+threadIdx.x;
    if (e < NE){ int d = ei[NE+e]; if ((unsigned)d < NN) atomicAdd(&cnt[d], 1); }
}

__global__ __launch_bounds__(256) void k_scan1(const int* __restrict__ cnt,
    int* __restrict__ iptr, int* __restrict__ bsum)
{
    __shared__ int s[256];
    int t = threadIdx.x, i = blockIdx.x*256 + t;
    int v = (i < NN) ? cnt[i] : 0;
    s[t] = v;
    for (int off=1; off<256; off<<=1){
        __syncthreads();
        int tv = (t >= off) ? s[t-off] : 0;
        __syncthreads();
        s[t] += tv;
    }
    __syncthreads();
    if (i < NN) iptr[i] = s[t] - v;
    if (t == 255) bsum[blockIdx.x] = s[255];
}

__global__ void k_scan2(int* bsum, int* iptr, int nb){
    if (threadIdx.x==0 && blockIdx.x==0){
        int run = 0;
        for (int b=0;b<nb;b++){ int v=bsum[b]; bsum[b]=run; run+=v; }
        iptr[NN] = run;
    }
}

__global__ void k_scan3(int* __restrict__ iptr, const int* __restrict__ bsum,
                        int* __restrict__ cur)
{
    int i = blockIdx.x*256 + threadIdx.x;
    if (i < NN){ int v = iptr[i] + bsum[i>>8]; iptr[i]=v; cur[i]=v; }
}

__global__ void k_scatter(const int* __restrict__ ei, int* __restrict__ cur,
                          int* __restrict__ esrc)
{
    int e = blockIdx.x*256 + threadIdx.x;
    if (e < NE){
        int d = ei[NE+e];
        if ((unsigned)d < NN){
            int p = atomicAdd(&cur[d], 1);
            if ((unsigned)p < NE) esrc[p] = ei[e];
        }
    }
}

// ---------------- GIN aggregation: h[i] = x[i] + sum_{e in in(i)} x[src(e)]
__global__ __launch_bounds__(128) void k_agg(const float* __restrict__ x,
    const int* __restrict__ iptr, const int* __restrict__ esrc, float* __restrict__ h)
{
    __shared__ int sl[128];
    int i = blockIdx.x, c = threadIdx.x;
    int s = iptr[i], e = iptr[i+1];
    s = max(0, min(s, NE));
    e = max(s, min(e, NE));
    float acc = x[(size_t)i*H + c];
    for (int base=s; base<e; base+=128){
        int nl = min(128, e-base);
        __syncthreads();
        if (c < nl) sl[c] = esrc[base+c];
        __syncthreads();
        for (int q=0;q<nl;q++){
            int idx = sl[q];
            idx = ((unsigned)idx < NN) ? idx : 0;
            acc += x[(size_t)idx*H + c];
        }
    }
    h[(size_t)i*H + c] = acc;
}

// ---------------- per-graph sum pooling ----------------
__global__ __launch_bounds__(128) void k_pool(const float* __restrict__ x,
    const int* __restrict__ batch, float* __restrict__ aggr)
{
    int g = blockIdx.x, c = threadIdx.x;
    int lo=0, hi=NN;
    while (lo<hi){ int mid=(lo+hi)>>1; if (batch[mid] < g) lo=mid+1; else hi=mid; }
    int s0 = lo;
    hi = NN;
    while (lo<hi){ int mid=(lo+hi)>>1; if (batch[mid] < g+1) lo=mid+1; else hi=mid; }
    int e0 = lo;
    float acc = 0.f;
    for (int i=s0;i<e0;i++) acc += x[(size_t)i*H + c];
    aggr[g*H + c] = acc;
}

// ---------------- 4 heads + evidential outputs (FP32 OUTPUT) ----------------
__global__ __launch_bounds__(128) void k_heads(const float* __restrict__ aggr,
    const float* __restrict__ W1, const float* __restrict__ b1,
    const float* __restrict__ W2, const float* __restrict__ b2,
    float* __restrict__ out)
{
    __shared__ float a[H];
    __shared__ float red[H];
    __shared__ float outk[4];
    int g = blockIdx.x, c = threadIdx.x;
    a[c] = aggr[g*H + c];
    __syncthreads();
    for (int k=0;k<4;k++){
        const float* w = W1 + k*H*H;
        float acc = b1[k*H + c];
#pragma unroll 4
        for (int q=0;q<H;q++) acc += a[q]*w[q*H + c];
        red[c] = fmaxf(acc, 0.f) * W2[k*H + c];
        __syncthreads();
        for (int sd=64; sd>0; sd>>=1){
            if (c < sd) red[c] += red[c+sd];
            __syncthreads();
        }
        if (c==0) outk[k] = red[0] + b2[k];
        __syncthreads();
    }
    if (c==0){
        float o0=outk[0], o1=outk[1], o2=outk[2], o3=outk[3];
        float alpha = fmaxf(softplusf(o0) + 1.f, 1.f + 1e-4f);
        float beta  = softplusf(o1);
        float nu    = softplusf(o2);
        float am1   = alpha - 1.f;
        float aleat = beta / am1;
        float epis  = beta / (am1 * nu);
        out[0*NG+g] = o3;      // gamma
        out[1*NG+g] = aleat;   // aleatoric
        out[2*NG+g] = epis;    // epistemic
        out[3*NG+g] = nu;
        out[4*NG+g] = alpha;
        out[5*NG+g] = beta;
    }
}

extern "C" void kernel_launch(void* const* d_in, const int* in_sizes, int n_in,
                              void* d_out, int out_size, void* d_ws, size_t ws_size,
                              hipStream_t stream)
{
    const int*   z     = (const int*)d_in[0];
    const float* pos   = (const float*)d_in[1];
    const int*   batch = (const int*)d_in[2];
    const int*   eidx  = (const int*)d_in[3];
    const float* emb   = (const float*)d_in[4];
    const float* Wp    = (const float*)d_in[5];
    const float* bp    = (const float*)d_in[6];
    const float* Wc    = (const float*)d_in[7];
    const float* bc    = (const float*)d_in[8];
    const float* gW1   = (const float*)d_in[9];
    const float* gb1   = (const float*)d_in[10];
    const float* gW2   = (const float*)d_in[11];
    const float* gb2   = (const float*)d_in[12];
    const float* hW1   = (const float*)d_in[13];
    const float* hb1   = (const float*)d_in[14];
    const float* hW2   = (const float*)d_in[15];
    const float* hb2   = (const float*)d_in[16];
    float* out = (float*)d_out;   // OUTPUT IS FLOAT32 (proved by R0/R4/R5 packing analysis)

    bool ok_sizes = (n_in == 17)
        && in_sizes[0] == NN && in_sizes[1] == NN*3 && in_sizes[2] == NN
        && in_sizes[3] == 2*NE && in_sizes[4] == 100*H
        && in_sizes[7] == 2*H*H && in_sizes[9] == 4*H*H
        && in_sizes[13] == 4*H*H && in_sizes[16] == 4;
    if (!ok_sizes){ k_sentinel<<<12, 256, 0, stream>>>(out, 600000.0f); return; }

    const size_t OFF_X    = 256;
    const size_t OFF_H    = 25600256;
    const size_t OFF_AGGR = 51200256;
    const size_t OFF_IPTR = 51462400;
    const size_t OFF_CUR  = 51662592;
    const size_t OFF_ESRC = 51862784;
    const size_t OFF_BSUM = 55062784;
    const size_t REQ      = 55063568;
    if (ws_size < REQ){ k_sentinel<<<12, 256, 0, stream>>>(out, 500000.0f); return; }

    char* ws = (char*)d_ws;
    float* x    = (float*)(ws + OFF_X);
    float* h    = (float*)(ws + OFF_H);
    float* aggr = (float*)(ws + OFF_AGGR);
    int*   iptr = (int*)(ws + OFF_IPTR);
    int*   cur  = (int*)(ws + OFF_CUR);
    int*   esrc = (int*)(ws + OFF_ESRC);
    int*   bsum = (int*)(ws + OFF_BSUM);

    k_embed<<<(NN+63)/64, 256, 0, stream>>>(z, pos, emb, Wp, bp, Wc, bc, x, NN);

    k_zero<<<(NN+255)/256, 256, 0, stream>>>(cur, NN);
    k_count<<<(NE+255)/256, 256, 0, stream>>>(eidx, cur);
    k_scan1<<<196, 256, 0, stream>>>(cur, iptr, bsum);
    k_scan2<<<1, 64, 0, stream>>>(bsum, iptr, 196);
    k_scan3<<<196, 256, 0, stream>>>(iptr, bsum, cur);
    k_scatter<<<(NE+255)/256, 256, 0, stream>>>(eidx, cur, esrc);

    for (int l=0;l<4;l++){
        k_agg<<<NN, 128, 0, stream>>>(x, iptr, esrc, h);
        k_gin_mlp<<<(NN+63)/64, 256, 0, stream>>>(h,
            gW1 + (size_t)l*H*H, gb1 + (size_t)l*H,
            gW2 + (size_t)l*H*H, gb2 + (size_t)l*H,
            x, NN, (l<3)?1:0);
    }

    k_pool<<<NG, 128, 0, stream>>>(x, batch, aggr);
    k_heads<<<NG, 128, 0, stream>>>(aggr, hW1, hb1, hW2, hb2, out);
}

// Round 7
// 871.903 us; speedup vs baseline: 1.0215x; 1.0215x over previous
//
#include <hip/hip_runtime.h>
#include <stdint.h>

#define NN 50000
#define NE 800000
#define NG 512
#define H  128

__device__ __forceinline__ float softplusf(float x){
    return fmaxf(x, 0.f) + log1pf(expf(-fabsf(x)));
}

// ---------------- sentinel writer (debug channel through out[.]) ----------------
__global__ void k_sentinel(float* out, float val){
    int i = blockIdx.x*256 + threadIdx.x;
    if (i < 6*NG) out[i] = val;
}

// ---------------- fused initial embedding GEMM ----------------
// x = relu( concat(embed_tab[z], pos@W_pos+b_pos) @ W_comb + b_comb )
// split-column Ws ownership {tn*4, 64+tn*4} -> 2-way LDS conflicts (free)
__global__ __launch_bounds__(256) void k_embed(const int* __restrict__ z,
    const float* __restrict__ pos, const float* __restrict__ emb,
    const float* __restrict__ Wp, const float* __restrict__ bp,
    const float* __restrict__ Wc, const float* __restrict__ bc,
    float* __restrict__ Y, int M)
{
    __shared__ float Xs[64*66];
    __shared__ float Ws[64*128];
    const int t  = threadIdx.x;
    const int tn = t & 15, tm = t >> 4;
    const int ca = tn*4, cb = 64 + tn*4;
    const int m0 = tm*4;
    const int mb = blockIdx.x*64;
    float acc[4][8];
#pragma unroll
    for (int i=0;i<4;i++)
#pragma unroll
      for (int j=0;j<8;j++) acc[i][j]=0.f;

    for (int k0=0; k0<256; k0+=64){
        {
            const int kq = t & 15, mr = t >> 4;
#pragma unroll
            for (int p=0;p<4;p++){
                int m = mr + p*16;
                int gr = mb + m;
                float4 v = make_float4(0.f,0.f,0.f,0.f);
                if (gr < M){
                    if (k0 < 128){
                        v = *(const float4*)(emb + (size_t)z[gr]*H + k0 + kq*4);
                    } else {
                        int c = (k0 - 128) + kq*4;
                        float4 w0 = *(const float4*)(Wp + c);
                        float4 w1 = *(const float4*)(Wp + H + c);
                        float4 w2 = *(const float4*)(Wp + 2*H + c);
                        float4 bb = *(const float4*)(bp + c);
                        float p0 = pos[gr*3+0], p1 = pos[gr*3+1], p2 = pos[gr*3+2];
                        v.x = p0*w0.x + p1*w1.x + p2*w2.x + bb.x;
                        v.y = p0*w0.y + p1*w1.y + p2*w2.y + bb.y;
                        v.z = p0*w0.z + p1*w1.z + p2*w2.z + bb.z;
                        v.w = p0*w0.w + p1*w1.w + p2*w2.w + bb.w;
                    }
                }
                float* d = &Xs[m*66 + kq*4];
                d[0]=v.x; d[1]=v.y; d[2]=v.z; d[3]=v.w;
            }
        }
        {
            const int kk = t >> 2, c0 = (t & 3)*32;
            const float4* wr = (const float4*)(Wc + (size_t)(k0+kk)*H + c0);
            float4* d = (float4*)&Ws[kk*H + c0];
#pragma unroll
            for (int q=0;q<8;q++) d[q] = wr[q];
        }
        __syncthreads();
#pragma unroll 8
        for (int kk=0; kk<64; kk++){
            float x0=Xs[(m0+0)*66+kk], x1=Xs[(m0+1)*66+kk];
            float x2=Xs[(m0+2)*66+kk], x3=Xs[(m0+3)*66+kk];
            float4 wa = *(const float4*)&Ws[kk*H + ca];
            float4 wb = *(const float4*)&Ws[kk*H + cb];
            float w[8] = {wa.x,wa.y,wa.z,wa.w, wb.x,wb.y,wb.z,wb.w};
#pragma unroll
            for (int j=0;j<8;j++){
                acc[0][j] += x0*w[j];
                acc[1][j] += x1*w[j];
                acc[2][j] += x2*w[j];
                acc[3][j] += x3*w[j];
            }
        }
        __syncthreads();
    }
    float4 bvA = *(const float4*)(bc + ca);
    float4 bvB = *(const float4*)(bc + cb);
    float bv[8] = {bvA.x,bvA.y,bvA.z,bvA.w, bvB.x,bvB.y,bvB.z,bvB.w};
#pragma unroll
    for (int i=0;i<4;i++){
        int gr = mb + m0 + i;
        if (gr < M){
            float o[8];
#pragma unroll
            for (int j=0;j<8;j++) o[j] = fmaxf(acc[i][j] + bv[j], 0.f);
            *(float4*)(Y + (size_t)gr*H + ca) = make_float4(o[0],o[1],o[2],o[3]);
            *(float4*)(Y + (size_t)gr*H + cb) = make_float4(o[4],o[5],o[6],o[7]);
        }
    }
}

// ---------------- fused GIN MLP v2: Y = act2( relu(Xin@W1+b1) @ W2 + b2 ) ----------------
// 128 threads, 64x128 block tile, 8x8 micro-tile.
// X kept TRANSPOSED in LDS: element [m][k] at Xt[k*68 + ((m + 8*((k>>2)&7)) & 63)]
//   -> per kk a wave reads 4x ds_read_b128 for 128 FMAs (LDS-cyc/FLOP 2.5x lower than v1)
// Ws staged in K=32 chunks; columns owned {tn*4, 64+tn*4} (2-way conflicts = free).
// LDS = 34816 + 16384 = 51200 B -> 3 blocks/CU.
__global__ __launch_bounds__(128) void k_gin_mlp(const float* __restrict__ Xin,
    const float* __restrict__ W1, const float* __restrict__ b1,
    const float* __restrict__ W2, const float* __restrict__ b2,
    float* __restrict__ Y, int M, int do_relu2)
{
    __shared__ float Xt[128*68];
    __shared__ float Wt[32*128];
    const int t  = threadIdx.x;
    const int tn = t & 15, tm = t >> 4;      // tn 0..15, tm 0..7
    const int ca = tn*4, cb = 64 + tn*4;
    const int m0 = tm*8;
    const int mb = blockIdx.x*64;

    // ---- stage X transposed+swizzled ----
#pragma unroll
    for (int q=0; q<16; q++){
        int f   = t + q*128;          // 0..2047
        int row = f >> 5;             // 0..63
        int k4  = f & 31;             // float4 index along K
        int k   = k4*4;
        float4 v = make_float4(0.f,0.f,0.f,0.f);
        int gr = mb + row;
        if (gr < M) v = *(const float4*)(Xin + (size_t)gr*H + k);
        int ms = (row + ((k4 & 7) << 3)) & 63;
        Xt[(k+0)*68 + ms] = v.x;
        Xt[(k+1)*68 + ms] = v.y;
        Xt[(k+2)*68 + ms] = v.z;
        Xt[(k+3)*68 + ms] = v.w;
    }

    float bb1[8], bb2[8];
    {
        float4 a = *(const float4*)(b1 + ca), b = *(const float4*)(b1 + cb);
        bb1[0]=a.x;bb1[1]=a.y;bb1[2]=a.z;bb1[3]=a.w;bb1[4]=b.x;bb1[5]=b.y;bb1[6]=b.z;bb1[7]=b.w;
        float4 c = *(const float4*)(b2 + ca), d = *(const float4*)(b2 + cb);
        bb2[0]=c.x;bb2[1]=c.y;bb2[2]=c.z;bb2[3]=c.w;bb2[4]=d.x;bb2[5]=d.y;bb2[6]=d.z;bb2[7]=d.w;
    }

    float acc[8][8];
#pragma unroll
    for (int i=0;i<8;i++)
#pragma unroll
      for (int j=0;j<8;j++) acc[i][j]=0.f;

    // ---- phase 1: T = relu(X@W1 + b1) ----
    { // stage first W chunk
        const float* Wsrc = W1;
#pragma unroll
        for (int q=0;q<8;q++){
            int f = t + q*128;            // 0..1023
            int kr = f >> 5, c4 = f & 31;
            *(float4*)&Wt[kr*128 + c4*4] = *(const float4*)(Wsrc + (size_t)kr*H + c4*4);
        }
    }
    __syncthreads();
    for (int chunk=0; chunk<4; chunk++){
        int k0 = chunk*32;
#pragma unroll 8
        for (int kk=0; kk<32; kk++){
            int k = k0 + kk;
            int msa = (m0 + (((kk>>2)&7)<<3)) & 63;
            const float4* xa = (const float4*)&Xt[k*68 + msa];
            float4 r0 = xa[0], r1 = xa[1];
            float4 wA = *(const float4*)&Wt[kk*128 + ca];
            float4 wB = *(const float4*)&Wt[kk*128 + cb];
            float xr[8] = {r0.x,r0.y,r0.z,r0.w, r1.x,r1.y,r1.z,r1.w};
            float wc[8] = {wA.x,wA.y,wA.z,wA.w, wB.x,wB.y,wB.z,wB.w};
#pragma unroll
            for (int i=0;i<8;i++)
#pragma unroll
              for (int j=0;j<8;j++) acc[i][j] += xr[i]*wc[j];
        }
        if (chunk < 3){
            __syncthreads();
            int nk0 = (chunk+1)*32;
#pragma unroll
            for (int q=0;q<8;q++){
                int f = t + q*128;
                int kr = f >> 5, c4 = f & 31;
                *(float4*)&Wt[kr*128 + c4*4] = *(const float4*)(W1 + (size_t)(nk0+kr)*H + c4*4);
            }
            __syncthreads();
        }
    }

    // ---- T -> Xt (transposed, same swizzle), stage first W2 chunk ----
    __syncthreads();
#pragma unroll
    for (int j=0;j<8;j++){
        int col = (j<4) ? (ca+j) : (cb+j-4);
        int s   = ((col>>2)&7)<<3;
        int mba = (m0 + s) & 63;
        float t0 = fmaxf(acc[0][j]+bb1[j],0.f), t1 = fmaxf(acc[1][j]+bb1[j],0.f);
        float t2 = fmaxf(acc[2][j]+bb1[j],0.f), t3 = fmaxf(acc[3][j]+bb1[j],0.f);
        float t4 = fmaxf(acc[4][j]+bb1[j],0.f), t5 = fmaxf(acc[5][j]+bb1[j],0.f);
        float t6 = fmaxf(acc[6][j]+bb1[j],0.f), t7 = fmaxf(acc[7][j]+bb1[j],0.f);
        *(float4*)&Xt[col*68 + mba]     = make_float4(t0,t1,t2,t3);
        *(float4*)&Xt[col*68 + mba + 4] = make_float4(t4,t5,t6,t7);
    }
#pragma unroll
    for (int q=0;q<8;q++){
        int f = t + q*128;
        int kr = f >> 5, c4 = f & 31;
        *(float4*)&Wt[kr*128 + c4*4] = *(const float4*)(W2 + (size_t)kr*H + c4*4);
    }
    __syncthreads();

#pragma unroll
    for (int i=0;i<8;i++)
#pragma unroll
      for (int j=0;j<8;j++) acc[i][j]=0.f;

    // ---- phase 2: Y = T@W2 + b2 ----
    for (int chunk=0; chunk<4; chunk++){
        int k0 = chunk*32;
#pragma unroll 8
        for (int kk=0; kk<32; kk++){
            int k = k0 + kk;
            int msa = (m0 + (((kk>>2)&7)<<3)) & 63;
            const float4* xa = (const float4*)&Xt[k*68 + msa];
            float4 r0 = xa[0], r1 = xa[1];
            float4 wA = *(const float4*)&Wt[kk*128 + ca];
            float4 wB = *(const float4*)&Wt[kk*128 + cb];
            float xr[8] = {r0.x,r0.y,r0.z,r0.w, r1.x,r1.y,r1.z,r1.w};
            float wc[8] = {wA.x,wA.y,wA.z,wA.w, wB.x,wB.y,wB.z,wB.w};
#pragma unroll
            for (int i=0;i<8;i++)
#pragma unroll
              for (int j=0;j<8;j++) acc[i][j] += xr[i]*wc[j];
        }
        if (chunk < 3){
            __syncthreads();
            int nk0 = (chunk+1)*32;
#pragma unroll
            for (int q=0;q<8;q++){
                int f = t + q*128;
                int kr = f >> 5, c4 = f & 31;
                *(float4*)&Wt[kr*128 + c4*4] = *(const float4*)(W2 + (size_t)(nk0+kr)*H + c4*4);
            }
            __syncthreads();
        }
    }

    // ---- epilogue ----
#pragma unroll
    for (int i=0;i<8;i++){
        int gr = mb + m0 + i;
        if (gr < M){
            float oA[4], oB[4];
#pragma unroll
            for (int j=0;j<4;j++){
                float v = acc[i][j] + bb2[j];
                oA[j] = do_relu2 ? fmaxf(v,0.f) : v;
            }
#pragma unroll
            for (int j=4;j<8;j++){
                float v = acc[i][j] + bb2[j];
                oB[j-4] = do_relu2 ? fmaxf(v,0.f) : v;
            }
            *(float4*)(Y + (size_t)gr*H + ca) = make_float4(oA[0],oA[1],oA[2],oA[3]);
            *(float4*)(Y + (size_t)gr*H + cb) = make_float4(oB[0],oB[1],oB[2],oB[3]);
        }
    }
}

// ---------------- CSR build (by dst) ----------------
__global__ void k_zero(int* p, int n){ int i=blockIdx.x*256+threadIdx.x; if(i<n) p[i]=0; }

__global__ void k_count(const int* __restrict__ ei, int* __restrict__ cnt){
    int e = blockIdx.x*256+threadIdx.x;
    if (e < NE){ int d = ei[NE+e]; if ((unsigned)d < NN) atomicAdd(&cnt[d], 1); }
}

__global__ __launch_bounds__(256) void k_scan1(const int* __restrict__ cnt,
    int* __restrict__ iptr, int* __restrict__ bsum)
{
    __shared__ int s[256];
    int t = threadIdx.x, i = blockIdx.x*256 + t;
    int v = (i < NN) ? cnt[i] : 0;
    s[t] = v;
    for (int off=1; off<256; off<<=1){
        __syncthreads();
        int tv = (t >= off) ? s[t-off] : 0;
        __syncthreads();
        s[t] += tv;
    }
    __syncthreads();
    if (i < NN) iptr[i] = s[t] - v;
    if (t == 255) bsum[blockIdx.x] = s[255];
}

__global__ void k_scan2(int* bsum, int* iptr, int nb){
    if (threadIdx.x==0 && blockIdx.x==0){
        int run = 0;
        for (int b=0;b<nb;b++){ int v=bsum[b]; bsum[b]=run; run+=v; }
        iptr[NN] = run;
    }
}

__global__ void k_scan3(int* __restrict__ iptr, const int* __restrict__ bsum,
                        int* __restrict__ cur)
{
    int i = blockIdx.x*256 + threadIdx.x;
    if (i < NN){ int v = iptr[i] + bsum[i>>8]; iptr[i]=v; cur[i]=v; }
}

__global__ void k_scatter(const int* __restrict__ ei, int* __restrict__ cur,
                          int* __restrict__ esrc)
{
    int e = blockIdx.x*256 + threadIdx.x;
    if (e < NE){
        int d = ei[NE+e];
        if ((unsigned)d < NN){
            int p = atomicAdd(&cur[d], 1);
            if ((unsigned)p < NE) esrc[p] = ei[e];
        }
    }
}

// ---------------- GIN aggregation v2: wave-per-node, float2 lanes ----------------
// h[i] = x[i] + sum_{e in in(i)} x[src(e)]; 4 nodes per 256-thread block.
__global__ __launch_bounds__(256) void k_agg(const float* __restrict__ x,
    const int* __restrict__ iptr, const int* __restrict__ esrc, float* __restrict__ h)
{
    int node = blockIdx.x*4 + (threadIdx.x >> 6);
    int lane = threadIdx.x & 63;
    int s = __builtin_amdgcn_readfirstlane(iptr[node]);
    int e = __builtin_amdgcn_readfirstlane(iptr[node+1]);
    const float2* __restrict__ xp = (const float2*)x;
    float2 acc = xp[(size_t)node*64 + lane];
    int j = s;
    for (; j+4 <= e; j += 4){
        int i0 = esrc[j+0], i1 = esrc[j+1], i2 = esrc[j+2], i3 = esrc[j+3];
        float2 v0 = xp[(size_t)i0*64 + lane];
        float2 v1 = xp[(size_t)i1*64 + lane];
        float2 v2 = xp[(size_t)i2*64 + lane];
        float2 v3 = xp[(size_t)i3*64 + lane];
        acc.x += (v0.x + v1.x) + (v2.x + v3.x);
        acc.y += (v0.y + v1.y) + (v2.y + v3.y);
    }
    for (; j < e; j++){
        int i0 = esrc[j];
        float2 v = xp[(size_t)i0*64 + lane];
        acc.x += v.x; acc.y += v.y;
    }
    ((float2*)h)[(size_t)node*64 + lane] = acc;
}

// ---------------- per-graph sum pooling (4-acc unroll) ----------------
__global__ __launch_bounds__(128) void k_pool(const float* __restrict__ x,
    const int* __restrict__ batch, float* __restrict__ aggr)
{
    int g = blockIdx.x, c = threadIdx.x;
    int lo=0, hi=NN;
    while (lo<hi){ int mid=(lo+hi)>>1; if (batch[mid] < g) lo=mid+1; else hi=mid; }
    int s0 = lo;
    hi = NN;
    while (lo<hi){ int mid=(lo+hi)>>1; if (batch[mid] < g+1) lo=mid+1; else hi=mid; }
    int e0 = lo;
    float a0=0.f, a1=0.f, a2=0.f, a3=0.f;
    int i = s0;
    for (; i+4 <= e0; i += 4){
        a0 += x[(size_t)(i+0)*H + c];
        a1 += x[(size_t)(i+1)*H + c];
        a2 += x[(size_t)(i+2)*H + c];
        a3 += x[(size_t)(i+3)*H + c];
    }
    for (; i < e0; i++) a0 += x[(size_t)i*H + c];
    aggr[g*H + c] = (a0+a1) + (a2+a3);
}

// ---------------- 4 heads + evidential outputs (FP32 OUTPUT) ----------------
__global__ __launch_bounds__(128) void k_heads(const float* __restrict__ aggr,
    const float* __restrict__ W1, const float* __restrict__ b1,
    const float* __restrict__ W2, const float* __restrict__ b2,
    float* __restrict__ out)
{
    __shared__ float a[H];
    __shared__ float red[H];
    __shared__ float outk[4];
    int g = blockIdx.x, c = threadIdx.x;
    a[c] = aggr[g*H + c];
    __syncthreads();
    for (int k=0;k<4;k++){
        const float* w = W1 + k*H*H;
        float acc = b1[k*H + c];
#pragma unroll 4
        for (int q=0;q<H;q++) acc += a[q]*w[q*H + c];
        red[c] = fmaxf(acc, 0.f) * W2[k*H + c];
        __syncthreads();
        for (int sd=64; sd>0; sd>>=1){
            if (c < sd) red[c] += red[c+sd];
            __syncthreads();
        }
        if (c==0) outk[k] = red[0] + b2[k];
        __syncthreads();
    }
    if (c==0){
        float o0=outk[0], o1=outk[1], o2=outk[2], o3=outk[3];
        float alpha = fmaxf(softplusf(o0) + 1.f, 1.f + 1e-4f);
        float beta  = softplusf(o1);
        float nu    = softplusf(o2);
        float am1   = alpha - 1.f;
        float aleat = beta / am1;
        float epis  = beta / (am1 * nu);
        out[0*NG+g] = o3;      // gamma
        out[1*NG+g] = aleat;   // aleatoric
        out[2*NG+g] = epis;    // epistemic
        out[3*NG+g] = nu;
        out[4*NG+g] = alpha;
        out[5*NG+g] = beta;
    }
}

extern "C" void kernel_launch(void* const* d_in, const int* in_sizes, int n_in,
                              void* d_out, int out_size, void* d_ws, size_t ws_size,
                              hipStream_t stream)
{
    const int*   z     = (const int*)d_in[0];
    const float* pos   = (const float*)d_in[1];
    const int*   batch = (const int*)d_in[2];
    const int*   eidx  = (const int*)d_in[3];
    const float* emb   = (const float*)d_in[4];
    const float* Wp    = (const float*)d_in[5];
    const float* bp    = (const float*)d_in[6];
    const float* Wc    = (const float*)d_in[7];
    const float* bc    = (const float*)d_in[8];
    const float* gW1   = (const float*)d_in[9];
    const float* gb1   = (const float*)d_in[10];
    const float* gW2   = (const float*)d_in[11];
    const float* gb2   = (const float*)d_in[12];
    const float* hW1   = (const float*)d_in[13];
    const float* hb1   = (const float*)d_in[14];
    const float* hW2   = (const float*)d_in[15];
    const float* hb2   = (const float*)d_in[16];
    float* out = (float*)d_out;   // fp32 output (verified R0/R4/R5)

    bool ok_sizes = (n_in == 17)
        && in_sizes[0] == NN && in_sizes[1] == NN*3 && in_sizes[2] == NN
        && in_sizes[3] == 2*NE && in_sizes[4] == 100*H
        && in_sizes[7] == 2*H*H && in_sizes[9] == 4*H*H
        && in_sizes[13] == 4*H*H && in_sizes[16] == 4;
    if (!ok_sizes){ k_sentinel<<<12, 256, 0, stream>>>(out, 600000.0f); return; }

    const size_t OFF_X    = 256;
    const size_t OFF_H    = 25600256;
    const size_t OFF_AGGR = 51200256;
    const size_t OFF_IPTR = 51462400;
    const size_t OFF_CUR  = 51662592;
    const size_t OFF_ESRC = 51862784;
    const size_t OFF_BSUM = 55062784;
    const size_t REQ      = 55063568;
    if (ws_size < REQ){ k_sentinel<<<12, 256, 0, stream>>>(out, 500000.0f); return; }

    char* ws = (char*)d_ws;
    float* x    = (float*)(ws + OFF_X);
    float* h    = (float*)(ws + OFF_H);
    float* aggr = (float*)(ws + OFF_AGGR);
    int*   iptr = (int*)(ws + OFF_IPTR);
    int*   cur  = (int*)(ws + OFF_CUR);
    int*   esrc = (int*)(ws + OFF_ESRC);
    int*   bsum = (int*)(ws + OFF_BSUM);

    k_embed<<<(NN+63)/64, 256, 0, stream>>>(z, pos, emb, Wp, bp, Wc, bc, x, NN);

    k_zero<<<(NN+255)/256, 256, 0, stream>>>(cur, NN);
    k_count<<<(NE+255)/256, 256, 0, stream>>>(eidx, cur);
    k_scan1<<<196, 256, 0, stream>>>(cur, iptr, bsum);
    k_scan2<<<1, 64, 0, stream>>>(bsum, iptr, 196);
    k_scan3<<<196, 256, 0, stream>>>(iptr, bsum, cur);
    k_scatter<<<(NE+255)/256, 256, 0, stream>>>(eidx, cur, esrc);

    for (int l=0;l<4;l++){
        k_agg<<<NN/4, 256, 0, stream>>>(x, iptr, esrc, h);
        k_gin_mlp<<<(NN+63)/64, 128, 0, stream>>>(h,
            gW1 + (size_t)l*H*H, gb1 + (size_t)l*H,
            gW2 + (size_t)l*H*H, gb2 + (size_t)l*H,
            x, NN, (l<3)?1:0);
    }

    k_pool<<<NG, 128, 0, stream>>>(x, batch, aggr);
    k_heads<<<NG, 128, 0, stream>>>(aggr, hW1, hb1, hW2, hb2, out);
}